// Round 1
// baseline (989.432 us; speedup 1.0000x reference)
//
#include <hip/hip_runtime.h>

#define D 256
#define GR 32   // rows per block in head kernel

// ---- transpose both weight matrices so k-loop reads are coalesced ----
__global__ void transpose_w_kernel(const float* __restrict__ lw, const float* __restrict__ sw,
                                   float* __restrict__ lwt, float* __restrict__ swt) {
    int k = blockIdx.x;   // source column -> dest row
    int j = threadIdx.x;  // source row    -> dest column (coalesced write)
    lwt[k * D + j] = lw[j * D + k];
    swt[k * D + j] = sw[j * D + k];
}

// ---- histogram of target indices ----
__global__ void hist_kernel(const int* __restrict__ tidx, int* __restrict__ cur, int E) {
    int e = blockIdx.x * blockDim.x + threadIdx.x;
    if (e < E) atomicAdd(&cur[tidx[e]], 1);
}

// ---- single-block exclusive scan over V counts (V=50000, 1024 threads) ----
__global__ void scan_kernel(int* __restrict__ cur, int* __restrict__ off, int V, int E) {
    __shared__ int sums[1024];
    int tid = threadIdx.x;
    int CH = (V + 1023) >> 10;
    int beg = tid * CH;
    int end = min(beg + CH, V);
    int s = 0;
    for (int i = beg; i < end; ++i) s += cur[i];
    sums[tid] = s;
    __syncthreads();
    // Hillis-Steele inclusive scan
    for (int ofs = 1; ofs < 1024; ofs <<= 1) {
        int v = (tid >= ofs) ? sums[tid - ofs] : 0;
        __syncthreads();
        sums[tid] += v;
        __syncthreads();
    }
    int run = (tid == 0) ? 0 : sums[tid - 1];
    for (int i = beg; i < end; ++i) {
        int c = cur[i];
        off[i] = run;   // bucket start
        cur[i] = run;   // fill cursor
        run += c;
    }
    if (tid == 1023) off[V] = E;
}

// ---- scatter edges into CSR buckets as packed {src, weight} records ----
__global__ void fill_kernel(const int* __restrict__ sidx, const int* __restrict__ tidx,
                            const float* __restrict__ esgn, const float* __restrict__ enorm,
                            int* __restrict__ cur, int2* __restrict__ pk, int E) {
    int e = blockIdx.x * blockDim.x + threadIdx.x;
    if (e >= E) return;
    int t = tidx[e];
    int idx = atomicAdd(&cur[t], 1);
    float w = enorm[e] * esgn[e];
    pk[idx] = make_int2(sidx[e], __float_as_int(w));
}

// ---- one wave per target node: gather rows, accumulate in regs, one store ----
__global__ __launch_bounds__(256) void accum_kernel(const float* __restrict__ vrepr,
                                                    const int2* __restrict__ pk,
                                                    const int* __restrict__ off,
                                                    float* __restrict__ ptrbuf, int V) {
    int gid = blockIdx.x * blockDim.x + threadIdx.x;
    int v = gid >> 6;
    int lane = threadIdx.x & 63;
    if (v >= V) return;
    int beg = off[v], end = off[v + 1];
    const float4* base = (const float4*)vrepr;
    float4 acc = make_float4(0.f, 0.f, 0.f, 0.f);
    int i = beg;
    for (; i + 2 <= end; i += 2) {   // unroll-2 for dual in-flight gathers
        int2 p0 = pk[i];
        int2 p1 = pk[i + 1];
        float w0 = __int_as_float(p0.y);
        float w1 = __int_as_float(p1.y);
        float4 a = base[(size_t)p0.x * 64 + lane];
        float4 b = base[(size_t)p1.x * 64 + lane];
        acc.x = fmaf(a.x, w0, acc.x); acc.y = fmaf(a.y, w0, acc.y);
        acc.z = fmaf(a.z, w0, acc.z); acc.w = fmaf(a.w, w0, acc.w);
        acc.x = fmaf(b.x, w1, acc.x); acc.y = fmaf(b.y, w1, acc.y);
        acc.z = fmaf(b.z, w1, acc.z); acc.w = fmaf(b.w, w1, acc.w);
    }
    if (i < end) {
        int2 p0 = pk[i];
        float w0 = __int_as_float(p0.y);
        float4 a = base[(size_t)p0.x * 64 + lane];
        acc.x = fmaf(a.x, w0, acc.x); acc.y = fmaf(a.y, w0, acc.y);
        acc.z = fmaf(a.z, w0, acc.z); acc.w = fmaf(a.w, w0, acc.w);
    }
    ((float4*)ptrbuf)[(size_t)v * 64 + lane] = acc;
}

// ---- fused dual-head GEMM + bias + softplus + rsample ----
__global__ __launch_bounds__(256) void head_kernel(const float* __restrict__ ptrv,
                                                   const float* __restrict__ lwt,
                                                   const float* __restrict__ swt,
                                                   const float* __restrict__ lb,
                                                   const float* __restrict__ sb,
                                                   const float* __restrict__ eps,
                                                   float* __restrict__ out, int V) {
    __shared__ float pt[GR][D];   // 32 KB row tile
    int v0 = blockIdx.x * GR;
    int j = threadIdx.x;          // output column 0..255

    const float4* src = (const float4*)ptrv;
    float4* dst = (float4*)&pt[0][0];
#pragma unroll
    for (int it = 0; it < (GR * 64) / 256; ++it) {
        int idx = it * 256 + threadIdx.x;
        int row = idx >> 6;
        int v = v0 + row;
        dst[idx] = (v < V) ? src[(size_t)v * 64 + (idx & 63)]
                           : make_float4(0.f, 0.f, 0.f, 0.f);
    }
    __syncthreads();

    float accL[GR], accS[GR];
#pragma unroll
    for (int r = 0; r < GR; ++r) { accL[r] = 0.f; accS[r] = 0.f; }

    for (int k = 0; k < D; k += 4) {
        float wl0 = lwt[(k + 0) * D + j];
        float wl1 = lwt[(k + 1) * D + j];
        float wl2 = lwt[(k + 2) * D + j];
        float wl3 = lwt[(k + 3) * D + j];
        float ws0 = swt[(k + 0) * D + j];
        float ws1 = swt[(k + 1) * D + j];
        float ws2 = swt[(k + 2) * D + j];
        float ws3 = swt[(k + 3) * D + j];
#pragma unroll
        for (int r = 0; r < GR; ++r) {
            float4 p = *(const float4*)&pt[r][k];   // LDS broadcast (all lanes same addr)
            accL[r] = fmaf(p.x, wl0, accL[r]);
            accL[r] = fmaf(p.y, wl1, accL[r]);
            accL[r] = fmaf(p.z, wl2, accL[r]);
            accL[r] = fmaf(p.w, wl3, accL[r]);
            accS[r] = fmaf(p.x, ws0, accS[r]);
            accS[r] = fmaf(p.y, ws1, accS[r]);
            accS[r] = fmaf(p.z, ws2, accS[r]);
            accS[r] = fmaf(p.w, ws3, accS[r]);
        }
    }

    size_t VD = (size_t)V * D;
    float lbj = lb[j];
    float sbj = sb[j];
#pragma unroll
    for (int r = 0; r < GR; ++r) {
        int v = v0 + r;
        if (v >= V) break;
        size_t o = (size_t)v * D + j;
        float lo = accL[r] + lbj;
        float pre = accS[r] + sbj;
        // numerically stable softplus: max(x,0) + log1p(exp(-|x|))
        float sp = fmaxf(pre, 0.f) + log1pf(expf(-fabsf(pre)));
        float st = sp + 1e-7f;
        float ep = eps[o];
        out[o] = lo;
        out[VD + o] = st;
        out[2 * VD + o] = fmaf(st, ep, lo);
    }
}

extern "C" void kernel_launch(void* const* d_in, const int* in_sizes, int n_in,
                              void* d_out, int out_size, void* d_ws, size_t ws_size,
                              hipStream_t stream) {
    const float* vrepr = (const float*)d_in[0];
    const int*   sidx  = (const int*)d_in[1];
    const int*   tidx  = (const int*)d_in[2];
    const float* esgn  = (const float*)d_in[3];
    const float* enorm = (const float*)d_in[4];
    const float* loc_w = (const float*)d_in[5];
    const float* loc_b = (const float*)d_in[6];
    const float* std_w = (const float*)d_in[7];
    const float* std_b = (const float*)d_in[8];
    const float* eps   = (const float*)d_in[9];
    float* out = (float*)d_out;

    int E = in_sizes[1];
    int V = in_sizes[0] / D;

    // workspace layout
    char* ws = (char*)d_ws;
    size_t o = 0;
    float* ptrbuf = (float*)(ws + o); o += (size_t)V * D * sizeof(float);   // 51.2 MB
    float* lwt    = (float*)(ws + o); o += (size_t)D * D * sizeof(float);
    float* swt    = (float*)(ws + o); o += (size_t)D * D * sizeof(float);
    int*   off    = (int*)(ws + o);   o += ((size_t)V + 16) * sizeof(int);
    int*   cur    = (int*)(ws + o);   o += ((size_t)V + 16) * sizeof(int);
    o = (o + 7) & ~(size_t)7;
    int2*  pk     = (int2*)(ws + o);  o += (size_t)E * sizeof(int2);        // 12.8 MB

    hipMemsetAsync(cur, 0, (size_t)V * sizeof(int), stream);
    transpose_w_kernel<<<D, D, 0, stream>>>(loc_w, std_w, lwt, swt);
    hist_kernel<<<(E + 255) / 256, 256, 0, stream>>>(tidx, cur, E);
    scan_kernel<<<1, 1024, 0, stream>>>(cur, off, V, E);
    fill_kernel<<<(E + 255) / 256, 256, 0, stream>>>(sidx, tidx, esgn, enorm, cur, pk, E);
    accum_kernel<<<(V * 64 + 255) / 256, 256, 0, stream>>>(vrepr, pk, off, ptrbuf, V);
    head_kernel<<<(V + GR - 1) / GR, 256, 0, stream>>>(ptrbuf, lwt, swt, loc_b, std_b, eps, out, V);
}

// Round 2
// 780.296 us; speedup vs baseline: 1.2680x; 1.2680x over previous
//
#include <hip/hip_runtime.h>

#define D 256
#define BM 128

typedef __attribute__((ext_vector_type(8))) short s16x8;
typedef __attribute__((ext_vector_type(4))) float f32x4;

static __device__ __forceinline__ float b2f(unsigned short u) {
    return __uint_as_float(((unsigned)u) << 16);
}
static __device__ __forceinline__ unsigned short f2b(float f) {
    unsigned u = __float_as_uint(f);
    unsigned r = (u + 0x7fffu + ((u >> 16) & 1u)) >> 16;   // RNE
    return (unsigned short)r;
}

// ---- cast both weight matrices to bf16 (they are already [n][k] row-major) ----
__global__ void prep_w_kernel(const float* __restrict__ lw, const float* __restrict__ sw,
                              unsigned short* __restrict__ wT) {
    int i = blockIdx.x * 256 + threadIdx.x;          // 0..131071
    float v = (i < D * D) ? lw[i] : sw[i - D * D];
    wT[i] = f2b(v);
}

// ---- cast vrepr to bf16 ----
__global__ void conv_v_kernel(const float* __restrict__ vr, unsigned short* __restrict__ vb, int n4) {
    int i = blockIdx.x * 256 + threadIdx.x;
    if (i < n4) {
        float4 f = ((const float4*)vr)[i];
        ushort4 o;
        o.x = f2b(f.x); o.y = f2b(f.y); o.z = f2b(f.z); o.w = f2b(f.w);
        ((ushort4*)vb)[i] = o;
    }
}

// ---- histogram of target indices ----
__global__ void hist_kernel(const int* __restrict__ tidx, int* __restrict__ cur, int E) {
    int e = blockIdx.x * blockDim.x + threadIdx.x;
    if (e < E) atomicAdd(&cur[tidx[e]], 1);
}

// ---- single-block exclusive scan over V counts ----
__global__ void scan_kernel(int* __restrict__ cur, int* __restrict__ off, int V, int E) {
    __shared__ int sums[1024];
    int tid = threadIdx.x;
    int CH = (V + 1023) >> 10;
    int beg = tid * CH;
    int end = min(beg + CH, V);
    int s = 0;
    for (int i = beg; i < end; ++i) s += cur[i];
    sums[tid] = s;
    __syncthreads();
    for (int ofs = 1; ofs < 1024; ofs <<= 1) {
        int v = (tid >= ofs) ? sums[tid - ofs] : 0;
        __syncthreads();
        sums[tid] += v;
        __syncthreads();
    }
    int run = (tid == 0) ? 0 : sums[tid - 1];
    for (int i = beg; i < end; ++i) {
        int c = cur[i];
        off[i] = run;
        cur[i] = run;
        run += c;
    }
    if (tid == 1023) off[V] = E;
}

// ---- scatter edges into CSR buckets as packed {src, weight} records ----
__global__ void fill_kernel(const int* __restrict__ sidx, const int* __restrict__ tidx,
                            const float* __restrict__ esgn, const float* __restrict__ enorm,
                            int* __restrict__ cur, int2* __restrict__ pk, int E) {
    int e = blockIdx.x * blockDim.x + threadIdx.x;
    if (e >= E) return;
    int t = tidx[e];
    int idx = atomicAdd(&cur[t], 1);
    float w = enorm[e] * esgn[e];
    pk[idx] = make_int2(sidx[e], __float_as_int(w));
}

// ---- one wave per target node: bf16 gather, fp32 accumulate, bf16 store ----
__global__ __launch_bounds__(256) void accum_kernel(const unsigned short* __restrict__ vb,
                                                    const int2* __restrict__ pk,
                                                    const int* __restrict__ off,
                                                    unsigned short* __restrict__ ptrb, int V) {
    int gid = blockIdx.x * blockDim.x + threadIdx.x;
    int v = gid >> 6;
    int lane = threadIdx.x & 63;
    if (v >= V) return;
    int beg = off[v], end = off[v + 1];
    const ushort4* base = (const ushort4*)vb;   // row = 64 ushort4
    float4 acc = make_float4(0.f, 0.f, 0.f, 0.f);
    int i = beg;
    for (; i + 2 <= end; i += 2) {
        int2 p0 = pk[i];
        int2 p1 = pk[i + 1];
        float w0 = __int_as_float(p0.y);
        float w1 = __int_as_float(p1.y);
        ushort4 a = base[(size_t)p0.x * 64 + lane];
        ushort4 b = base[(size_t)p1.x * 64 + lane];
        acc.x = fmaf(b2f(a.x), w0, acc.x); acc.y = fmaf(b2f(a.y), w0, acc.y);
        acc.z = fmaf(b2f(a.z), w0, acc.z); acc.w = fmaf(b2f(a.w), w0, acc.w);
        acc.x = fmaf(b2f(b.x), w1, acc.x); acc.y = fmaf(b2f(b.y), w1, acc.y);
        acc.z = fmaf(b2f(b.z), w1, acc.z); acc.w = fmaf(b2f(b.w), w1, acc.w);
    }
    if (i < end) {
        int2 p0 = pk[i];
        float w0 = __int_as_float(p0.y);
        ushort4 a = base[(size_t)p0.x * 64 + lane];
        acc.x = fmaf(b2f(a.x), w0, acc.x); acc.y = fmaf(b2f(a.y), w0, acc.y);
        acc.z = fmaf(b2f(a.z), w0, acc.z); acc.w = fmaf(b2f(a.w), w0, acc.w);
    }
    ushort4 o;
    o.x = f2b(acc.x); o.y = f2b(acc.y); o.z = f2b(acc.z); o.w = f2b(acc.w);
    ((ushort4*)ptrb)[(size_t)v * 64 + lane] = o;
}

// ---- MFMA dual-head GEMM + bias + softplus + rsample ----
// Block: 128 rows x (64 loc cols + 64 std cols). Wave w: rows w*32..w*32+31.
__global__ __launch_bounds__(256) void head_mfma_kernel(const unsigned short* __restrict__ ptrb,
                                                        const unsigned short* __restrict__ wT,
                                                        const float* __restrict__ lb,
                                                        const float* __restrict__ sb,
                                                        const float* __restrict__ eps,
                                                        float* __restrict__ out, int V) {
    __shared__ unsigned short lA[BM][72];   // 128 rows x 64 bf16 (+8 pad)
    __shared__ unsigned short lB[BM][72];   // rows 0..63 = loc W, 64..127 = std W
    int v0 = blockIdx.x * BM;
    int c0 = blockIdx.y * 64;               // column range of each head
    int tid = threadIdx.x;
    int wave = tid >> 6, lane = tid & 63;
    int quad = lane >> 4, m16 = lane & 15;

    f32x4 acc[2][8];
    f32x4 zero = {0.f, 0.f, 0.f, 0.f};
#pragma unroll
    for (int i = 0; i < 2; ++i)
#pragma unroll
        for (int j = 0; j < 8; ++j) acc[i][j] = zero;

    for (int k0 = 0; k0 < D; k0 += 64) {
#pragma unroll
        for (int it = 0; it < 4; ++it) {
            int c = it * 256 + tid;         // 0..1023 chunks of 16B
            int m = c >> 3, kc = (c & 7) * 8;
            int v = v0 + m;
            uint4 val = make_uint4(0, 0, 0, 0);
            if (v < V) val = *(const uint4*)(ptrb + (size_t)v * D + k0 + kc);
            *(uint4*)&lA[m][kc] = val;
            int nsrc = (m < 64) ? (c0 + m) : (D + c0 + (m - 64));
            *(uint4*)&lB[m][kc] = *(const uint4*)(wT + (size_t)nsrc * D + k0 + kc);
        }
        __syncthreads();
#pragma unroll
        for (int kk = 0; kk < 2; ++kk) {
            int kb = kk * 32 + quad * 8;
            s16x8 a0 = *(const s16x8*)&lA[wave * 32 + m16][kb];
            s16x8 a1 = *(const s16x8*)&lA[wave * 32 + 16 + m16][kb];
            s16x8 b[8];
#pragma unroll
            for (int nt = 0; nt < 8; ++nt)
                b[nt] = *(const s16x8*)&lB[nt * 16 + m16][kb];
#pragma unroll
            for (int nt = 0; nt < 8; ++nt) {
                acc[0][nt] = __builtin_amdgcn_mfma_f32_16x16x32_bf16(a0, b[nt], acc[0][nt], 0, 0, 0);
                acc[1][nt] = __builtin_amdgcn_mfma_f32_16x16x32_bf16(a1, b[nt], acc[1][nt], 0, 0, 0);
            }
        }
        __syncthreads();
    }

    size_t VD = (size_t)V * D;
#pragma unroll
    for (int mt = 0; mt < 2; ++mt) {
#pragma unroll
        for (int nt = 0; nt < 4; ++nt) {
            int cc = c0 + nt * 16 + m16;
            float lbj = lb[cc], sbj = sb[cc];
#pragma unroll
            for (int r = 0; r < 4; ++r) {
                int v = v0 + wave * 32 + mt * 16 + quad * 4 + r;
                if (v < V) {
                    size_t o = (size_t)v * D + cc;
                    float lo = acc[mt][nt][r] + lbj;
                    float pre = acc[mt][nt + 4][r] + sbj;
                    float sp = fmaxf(pre, 0.f) + log1pf(expf(-fabsf(pre)));
                    float st = sp + 1e-7f;
                    out[o] = lo;
                    out[VD + o] = st;
                    out[2 * VD + o] = fmaf(st, eps[o], lo);
                }
            }
        }
    }
}

extern "C" void kernel_launch(void* const* d_in, const int* in_sizes, int n_in,
                              void* d_out, int out_size, void* d_ws, size_t ws_size,
                              hipStream_t stream) {
    const float* vrepr = (const float*)d_in[0];
    const int*   sidx  = (const int*)d_in[1];
    const int*   tidx  = (const int*)d_in[2];
    const float* esgn  = (const float*)d_in[3];
    const float* enorm = (const float*)d_in[4];
    const float* loc_w = (const float*)d_in[5];
    const float* loc_b = (const float*)d_in[6];
    const float* std_w = (const float*)d_in[7];
    const float* std_b = (const float*)d_in[8];
    const float* eps   = (const float*)d_in[9];
    float* out = (float*)d_out;

    int E = in_sizes[1];
    int V = in_sizes[0] / D;

    char* ws = (char*)d_ws;
    size_t o = 0;
    unsigned short* vb   = (unsigned short*)(ws + o); o += (size_t)V * D * 2;      // 25.6 MB
    unsigned short* ptrb = (unsigned short*)(ws + o); o += (size_t)V * D * 2;      // 25.6 MB
    unsigned short* wT   = (unsigned short*)(ws + o); o += (size_t)2 * D * D * 2;  // 256 KB
    int* off = (int*)(ws + o); o += ((size_t)V + 16) * sizeof(int);
    int* cur = (int*)(ws + o); o += ((size_t)V + 16) * sizeof(int);
    o = (o + 15) & ~(size_t)15;
    int2* pk = (int2*)(ws + o); o += (size_t)E * sizeof(int2);                     // 12.8 MB

    hipMemsetAsync(cur, 0, (size_t)V * sizeof(int), stream);
    prep_w_kernel<<<(2 * D * D) / 256, 256, 0, stream>>>(loc_w, std_w, wT);
    conv_v_kernel<<<(V * (D / 4) + 255) / 256, 256, 0, stream>>>(vrepr, vb, V * (D / 4));
    hist_kernel<<<(E + 255) / 256, 256, 0, stream>>>(tidx, cur, E);
    scan_kernel<<<1, 1024, 0, stream>>>(cur, off, V, E);
    fill_kernel<<<(E + 255) / 256, 256, 0, stream>>>(sidx, tidx, esgn, enorm, cur, pk, E);
    accum_kernel<<<(V * 64 + 255) / 256, 256, 0, stream>>>(vb, pk, off, ptrb, V);
    dim3 hgrid((V + BM - 1) / BM, 4);
    head_mfma_kernel<<<hgrid, 256, 0, stream>>>(ptrb, wT, loc_b, std_b, eps, out, V);
}

// Round 3
// 757.562 us; speedup vs baseline: 1.3061x; 1.0300x over previous
//
#include <hip/hip_runtime.h>

#define D 256
#define BM 128

typedef __attribute__((ext_vector_type(8))) short s16x8;
typedef __attribute__((ext_vector_type(4))) float f32x4;

static __device__ __forceinline__ unsigned short f2b(float f) {
    unsigned u = __float_as_uint(f);
    unsigned r = (u + 0x7fffu + ((u >> 16) & 1u)) >> 16;   // RNE
    return (unsigned short)r;
}
static __device__ __forceinline__ unsigned pack2(float a, float b) {
    return (unsigned)f2b(a) | ((unsigned)f2b(b) << 16);
}

// ---- cast both weight matrices to bf16 (already [n][k] row-major) ----
__global__ void prep_w_kernel(const float* __restrict__ lw, const float* __restrict__ sw,
                              unsigned short* __restrict__ wT) {
    int i = blockIdx.x * 256 + threadIdx.x;
    float v = (i < D * D) ? lw[i] : sw[i - D * D];
    wT[i] = f2b(v);
}

// ---- cast vrepr to bf16, 32B read / 16B write per thread ----
__global__ void conv_v_kernel(const float* __restrict__ vr, unsigned short* __restrict__ vb, int n8) {
    int i = blockIdx.x * 256 + threadIdx.x;
    if (i < n8) {
        float4 f0 = ((const float4*)vr)[2 * i];
        float4 f1 = ((const float4*)vr)[2 * i + 1];
        uint4 o;
        o.x = pack2(f0.x, f0.y);
        o.y = pack2(f0.z, f0.w);
        o.z = pack2(f1.x, f1.y);
        o.w = pack2(f1.z, f1.w);
        ((uint4*)vb)[i] = o;
    }
}

// ---- histogram of target indices ----
__global__ void hist_kernel(const int* __restrict__ tidx, int* __restrict__ cur, int E) {
    int e = blockIdx.x * blockDim.x + threadIdx.x;
    if (e < E) atomicAdd(&cur[tidx[e]], 1);
}

// ---- single-block exclusive scan over V counts ----
__global__ void scan_kernel(int* __restrict__ cur, int* __restrict__ off, int V, int E) {
    __shared__ int sums[1024];
    int tid = threadIdx.x;
    int CH = (V + 1023) >> 10;
    int beg = tid * CH;
    int end = min(beg + CH, V);
    int s = 0;
    for (int i = beg; i < end; ++i) s += cur[i];
    sums[tid] = s;
    __syncthreads();
    for (int ofs = 1; ofs < 1024; ofs <<= 1) {
        int v = (tid >= ofs) ? sums[tid - ofs] : 0;
        __syncthreads();
        sums[tid] += v;
        __syncthreads();
    }
    int run = (tid == 0) ? 0 : sums[tid - 1];
    for (int i = beg; i < end; ++i) {
        int c = cur[i];
        off[i] = run;
        cur[i] = run;
        run += c;
    }
    if (tid == 1023) off[V] = E;
}

// ---- scatter edges into CSR buckets as packed {src, weight} records ----
__global__ void fill_kernel(const int* __restrict__ sidx, const int* __restrict__ tidx,
                            const float* __restrict__ esgn, const float* __restrict__ enorm,
                            int* __restrict__ cur, int2* __restrict__ pk, int E) {
    int e = blockIdx.x * blockDim.x + threadIdx.x;
    if (e >= E) return;
    int t = tidx[e];
    int idx = atomicAdd(&cur[t], 1);
    float w = enorm[e] * esgn[e];
    pk[idx] = make_int2(sidx[e], __float_as_int(w));
}

// ---- one wave per target node: 16B bf16 gathers, 2 edges/iter, fp32 accum ----
__global__ __launch_bounds__(256) void accum_kernel(const unsigned short* __restrict__ vb,
                                                    const int2* __restrict__ pk,
                                                    const int* __restrict__ off,
                                                    unsigned short* __restrict__ ptrb, int V) {
    int gid = blockIdx.x * blockDim.x + threadIdx.x;
    int v = gid >> 6;
    if (v >= V) return;
    int lane = threadIdx.x & 63;
    int half = lane >> 5;     // edge parity handled by this half-wave
    int c = lane & 31;        // 16B chunk (8 bf16) within the row
    int beg = off[v], end = off[v + 1];
    const uint4* base = (const uint4*)vb;   // row = 32 uint4
    float acc[8];
#pragma unroll
    for (int j = 0; j < 8; ++j) acc[j] = 0.f;
    for (int i = beg + half; i < end; i += 2) {
        int2 p = pk[i];
        float w = __int_as_float(p.y);
        uint4 a = base[(size_t)p.x * 32 + c];
        acc[0] = fmaf(__uint_as_float(a.x << 16), w, acc[0]);
        acc[1] = fmaf(__uint_as_float(a.x & 0xffff0000u), w, acc[1]);
        acc[2] = fmaf(__uint_as_float(a.y << 16), w, acc[2]);
        acc[3] = fmaf(__uint_as_float(a.y & 0xffff0000u), w, acc[3]);
        acc[4] = fmaf(__uint_as_float(a.z << 16), w, acc[4]);
        acc[5] = fmaf(__uint_as_float(a.z & 0xffff0000u), w, acc[5]);
        acc[6] = fmaf(__uint_as_float(a.w << 16), w, acc[6]);
        acc[7] = fmaf(__uint_as_float(a.w & 0xffff0000u), w, acc[7]);
    }
#pragma unroll
    for (int j = 0; j < 8; ++j) acc[j] += __shfl_xor(acc[j], 32, 64);
    if (half == 0) {
        uint4 o;
        o.x = pack2(acc[0], acc[1]);
        o.y = pack2(acc[2], acc[3]);
        o.z = pack2(acc[4], acc[5]);
        o.w = pack2(acc[6], acc[7]);
        *(uint4*)(ptrb + (size_t)v * D + c * 8) = o;
    }
}

// ---- MFMA dual-head GEMM + bias + softplus + rsample, register-prefetch pipeline ----
// grid.x = 4 column groups (64 loc + matching 64 std cols), grid.y = row tiles of 128.
__global__ __launch_bounds__(256) void head_mfma_kernel(const unsigned short* __restrict__ ptrb,
                                                        const unsigned short* __restrict__ wT,
                                                        const float* __restrict__ lb,
                                                        const float* __restrict__ sb,
                                                        const float* __restrict__ eps,
                                                        float* __restrict__ out, int V) {
    __shared__ unsigned short lA[BM][72];   // 128 rows x 64 bf16 (+8 pad)
    __shared__ unsigned short lB[BM][72];   // rows 0..63 loc W, 64..127 std W
    int c0 = blockIdx.x * 64;
    int v0 = blockIdx.y * BM;
    int tid = threadIdx.x;
    int wave = tid >> 6, lane = tid & 63;
    int quad = lane >> 4, m16 = lane & 15;
    bool fullA = (v0 + BM <= V);

    // per-thread staging coordinates (4 chunks of 16B for A, 4 for B)
    int sc_m[4], sc_kc[4], sc_n[4];
#pragma unroll
    for (int it = 0; it < 4; ++it) {
        int cc = it * 256 + tid;        // 0..1023
        int m = cc >> 3, kc = (cc & 7) * 8;
        sc_m[it] = m; sc_kc[it] = kc;
        sc_n[it] = (m < 64) ? (c0 + m) : (D + c0 + (m - 64));
    }

    uint4 ra[4], rb[4];
#pragma unroll
    for (int it = 0; it < 4; ++it) {
        int vv = v0 + sc_m[it];
        ra[it] = (fullA || vv < V) ? *(const uint4*)(ptrb + (size_t)vv * D + sc_kc[it])
                                   : make_uint4(0, 0, 0, 0);
        rb[it] = *(const uint4*)(wT + (size_t)sc_n[it] * D + sc_kc[it]);
    }

    f32x4 acc[2][8];
    f32x4 zero = {0.f, 0.f, 0.f, 0.f};
#pragma unroll
    for (int i = 0; i < 2; ++i)
#pragma unroll
        for (int j = 0; j < 8; ++j) acc[i][j] = zero;

    for (int k0i = 0; k0i < 4; ++k0i) {
        if (k0i) __syncthreads();       // previous tile's reads complete
#pragma unroll
        for (int it = 0; it < 4; ++it) {
            *(uint4*)&lA[sc_m[it]][sc_kc[it]] = ra[it];
            *(uint4*)&lB[sc_m[it]][sc_kc[it]] = rb[it];
        }
        __syncthreads();
        if (k0i < 3) {                  // prefetch next tile; overlaps MFMAs below
            int k0 = (k0i + 1) * 64;
#pragma unroll
            for (int it = 0; it < 4; ++it) {
                int vv = v0 + sc_m[it];
                ra[it] = (fullA || vv < V) ? *(const uint4*)(ptrb + (size_t)vv * D + k0 + sc_kc[it])
                                           : make_uint4(0, 0, 0, 0);
                rb[it] = *(const uint4*)(wT + (size_t)sc_n[it] * D + k0 + sc_kc[it]);
            }
        }
#pragma unroll
        for (int kk = 0; kk < 2; ++kk) {
            int kb = kk * 32 + quad * 8;
            s16x8 a0 = *(const s16x8*)&lA[wave * 32 + m16][kb];
            s16x8 a1 = *(const s16x8*)&lA[wave * 32 + 16 + m16][kb];
#pragma unroll
            for (int nt = 0; nt < 8; ++nt) {
                s16x8 b = *(const s16x8*)&lB[nt * 16 + m16][kb];
                acc[0][nt] = __builtin_amdgcn_mfma_f32_16x16x32_bf16(a0, b, acc[0][nt], 0, 0, 0);
                acc[1][nt] = __builtin_amdgcn_mfma_f32_16x16x32_bf16(a1, b, acc[1][nt], 0, 0, 0);
            }
        }
    }

    // epilogue
    size_t VD = (size_t)V * D;
    float lbv[4], sbv[4];
#pragma unroll
    for (int nt = 0; nt < 4; ++nt) {
        int cc = c0 + nt * 16 + m16;
        lbv[nt] = lb[cc];
        sbv[nt] = sb[cc];
    }
    const float* epsb = eps + (size_t)v0 * D;
    float* outb = out + (size_t)v0 * D;
#pragma unroll
    for (int mt = 0; mt < 2; ++mt) {
#pragma unroll
        for (int nt = 0; nt < 4; ++nt) {
#pragma unroll
            for (int r = 0; r < 4; ++r) {
                int row = wave * 32 + mt * 16 + quad * 4 + r;
                if (fullA || v0 + row < V) {
                    int o = row * D + c0 + nt * 16 + m16;
                    float lo = acc[mt][nt][r] + lbv[nt];
                    float pre = acc[mt][nt + 4][r] + sbv[nt];
                    float sp = fmaxf(pre, 0.f) + __logf(1.f + __expf(-fabsf(pre)));
                    float st = sp + 1e-7f;
                    outb[o] = lo;
                    outb[VD + o] = st;
                    outb[2 * VD + o] = fmaf(st, epsb[o], lo);
                }
            }
        }
    }
}

extern "C" void kernel_launch(void* const* d_in, const int* in_sizes, int n_in,
                              void* d_out, int out_size, void* d_ws, size_t ws_size,
                              hipStream_t stream) {
    const float* vrepr = (const float*)d_in[0];
    const int*   sidx  = (const int*)d_in[1];
    const int*   tidx  = (const int*)d_in[2];
    const float* esgn  = (const float*)d_in[3];
    const float* enorm = (const float*)d_in[4];
    const float* loc_w = (const float*)d_in[5];
    const float* loc_b = (const float*)d_in[6];
    const float* std_w = (const float*)d_in[7];
    const float* std_b = (const float*)d_in[8];
    const float* eps   = (const float*)d_in[9];
    float* out = (float*)d_out;

    int E = in_sizes[1];
    int V = in_sizes[0] / D;

    char* ws = (char*)d_ws;
    size_t o = 0;
    unsigned short* vb   = (unsigned short*)(ws + o); o += (size_t)V * D * 2;
    unsigned short* ptrb = (unsigned short*)(ws + o); o += (size_t)V * D * 2;
    unsigned short* wT   = (unsigned short*)(ws + o); o += (size_t)2 * D * D * 2;
    int* off = (int*)(ws + o); o += ((size_t)V + 16) * sizeof(int);
    int* cur = (int*)(ws + o); o += ((size_t)V + 16) * sizeof(int);
    o = (o + 15) & ~(size_t)15;
    int2* pk = (int2*)(ws + o); o += (size_t)E * sizeof(int2);

    hipMemsetAsync(cur, 0, (size_t)V * sizeof(int), stream);
    prep_w_kernel<<<(2 * D * D) / 256, 256, 0, stream>>>(loc_w, std_w, wT);
    conv_v_kernel<<<(V * (D / 8) + 255) / 256, 256, 0, stream>>>(vrepr, vb, V * (D / 8));
    hist_kernel<<<(E + 255) / 256, 256, 0, stream>>>(tidx, cur, E);
    scan_kernel<<<1, 1024, 0, stream>>>(cur, off, V, E);
    fill_kernel<<<(E + 255) / 256, 256, 0, stream>>>(sidx, tidx, esgn, enorm, cur, pk, E);
    accum_kernel<<<(V * 64 + 255) / 256, 256, 0, stream>>>(vb, pk, off, ptrb, V);
    dim3 hgrid(4, (V + BM - 1) / BM);
    head_mfma_kernel<<<hgrid, 256, 0, stream>>>(ptrb, wT, loc_b, std_b, eps, out, V);
}

// Round 4
// 634.727 us; speedup vs baseline: 1.5588x; 1.1935x over previous
//
#include <hip/hip_runtime.h>

#define D 256
#define BM 128

typedef __attribute__((ext_vector_type(8))) short s16x8;
typedef __attribute__((ext_vector_type(4))) float f32x4;

static __device__ __forceinline__ unsigned short f2b(float f) {
    unsigned u = __float_as_uint(f);
    unsigned r = (u + 0x7fffu + ((u >> 16) & 1u)) >> 16;   // RNE
    return (unsigned short)r;
}
static __device__ __forceinline__ unsigned pack2(float a, float b) {
    return (unsigned)f2b(a) | ((unsigned)f2b(b) << 16);
}

// ---- cast both weight matrices to bf16 (already [n][k] row-major) ----
__global__ void prep_w_kernel(const float* __restrict__ lw, const float* __restrict__ sw,
                              unsigned short* __restrict__ wT) {
    int i = blockIdx.x * 256 + threadIdx.x;
    float v = (i < D * D) ? lw[i] : sw[i - D * D];
    wT[i] = f2b(v);
}

// ---- cast vrepr to bf16, 32B read / 16B write per thread ----
__global__ void conv_v_kernel(const float* __restrict__ vr, unsigned short* __restrict__ vb, int n8) {
    int i = blockIdx.x * 256 + threadIdx.x;
    if (i < n8) {
        float4 f0 = ((const float4*)vr)[2 * i];
        float4 f1 = ((const float4*)vr)[2 * i + 1];
        uint4 o;
        o.x = pack2(f0.x, f0.y);
        o.y = pack2(f0.z, f0.w);
        o.z = pack2(f1.x, f1.y);
        o.w = pack2(f1.z, f1.w);
        ((uint4*)vb)[i] = o;
    }
}

// ---- histogram of target indices; records each edge's arrival rank ----
__global__ void hist_kernel(const int* __restrict__ tidx, int* __restrict__ cnt,
                            int* __restrict__ rank, int E) {
    int e = blockIdx.x * blockDim.x + threadIdx.x;
    if (e < E) rank[e] = atomicAdd(&cnt[tidx[e]], 1);
}

// ---- single-block exclusive scan over V counts ----
__global__ void scan_kernel(const int* __restrict__ cnt, int* __restrict__ off, int V, int E) {
    __shared__ int sums[1024];
    int tid = threadIdx.x;
    int CH = (V + 1023) >> 10;
    int beg = tid * CH;
    int end = min(beg + CH, V);
    int s = 0;
    for (int i = beg; i < end; ++i) s += cnt[i];
    sums[tid] = s;
    __syncthreads();
    for (int ofs = 1; ofs < 1024; ofs <<= 1) {
        int v = (tid >= ofs) ? sums[tid - ofs] : 0;
        __syncthreads();
        sums[tid] += v;
        __syncthreads();
    }
    int run = (tid == 0) ? 0 : sums[tid - 1];
    for (int i = beg; i < end; ++i) {
        off[i] = run;
        run += cnt[i];
    }
    if (tid == 1023) off[V] = E;
}

// ---- scatter edges into CSR buckets (atomic-free: off[t] + rank[e]) ----
__global__ void fill_kernel(const int* __restrict__ sidx, const int* __restrict__ tidx,
                            const float* __restrict__ esgn, const float* __restrict__ enorm,
                            const int* __restrict__ off, const int* __restrict__ rank,
                            int2* __restrict__ pk, int E) {
    int e = blockIdx.x * blockDim.x + threadIdx.x;
    if (e >= E) return;
    int idx = off[tidx[e]] + rank[e];
    float w = enorm[e] * esgn[e];
    pk[idx] = make_int2(sidx[e], __float_as_int(w));
}

// ---- one wave per target node: 16B bf16 gathers, 4 edges in flight/wave ----
__global__ __launch_bounds__(256) void accum_kernel(const unsigned short* __restrict__ vb,
                                                    const int2* __restrict__ pk,
                                                    const int* __restrict__ off,
                                                    unsigned short* __restrict__ ptrb, int V) {
    int gid = blockIdx.x * blockDim.x + threadIdx.x;
    int v = gid >> 6;
    if (v >= V) return;
    int lane = threadIdx.x & 63;
    int half = lane >> 5;     // edge parity handled by this half-wave
    int c = lane & 31;        // 16B chunk (8 bf16) within the row
    int beg = off[v], end = off[v + 1];
    const uint4* base = (const uint4*)vb;   // row = 32 uint4
    float acc[8];
#pragma unroll
    for (int j = 0; j < 8; ++j) acc[j] = 0.f;
    int i = beg + half;
    for (; i + 2 < end; i += 4) {            // 2 independent chains per half-wave
        int2 p0 = pk[i];
        int2 p1 = pk[i + 2];
        float w0 = __int_as_float(p0.y);
        float w1 = __int_as_float(p1.y);
        uint4 a = base[(size_t)p0.x * 32 + c];
        uint4 b = base[(size_t)p1.x * 32 + c];
        acc[0] = fmaf(__uint_as_float(a.x << 16), w0, acc[0]);
        acc[1] = fmaf(__uint_as_float(a.x & 0xffff0000u), w0, acc[1]);
        acc[2] = fmaf(__uint_as_float(a.y << 16), w0, acc[2]);
        acc[3] = fmaf(__uint_as_float(a.y & 0xffff0000u), w0, acc[3]);
        acc[4] = fmaf(__uint_as_float(a.z << 16), w0, acc[4]);
        acc[5] = fmaf(__uint_as_float(a.z & 0xffff0000u), w0, acc[5]);
        acc[6] = fmaf(__uint_as_float(a.w << 16), w0, acc[6]);
        acc[7] = fmaf(__uint_as_float(a.w & 0xffff0000u), w0, acc[7]);
        acc[0] = fmaf(__uint_as_float(b.x << 16), w1, acc[0]);
        acc[1] = fmaf(__uint_as_float(b.x & 0xffff0000u), w1, acc[1]);
        acc[2] = fmaf(__uint_as_float(b.y << 16), w1, acc[2]);
        acc[3] = fmaf(__uint_as_float(b.y & 0xffff0000u), w1, acc[3]);
        acc[4] = fmaf(__uint_as_float(b.z << 16), w1, acc[4]);
        acc[5] = fmaf(__uint_as_float(b.z & 0xffff0000u), w1, acc[5]);
        acc[6] = fmaf(__uint_as_float(b.w << 16), w1, acc[6]);
        acc[7] = fmaf(__uint_as_float(b.w & 0xffff0000u), w1, acc[7]);
    }
    if (i < end) {
        int2 p = pk[i];
        float w = __int_as_float(p.y);
        uint4 a = base[(size_t)p.x * 32 + c];
        acc[0] = fmaf(__uint_as_float(a.x << 16), w, acc[0]);
        acc[1] = fmaf(__uint_as_float(a.x & 0xffff0000u), w, acc[1]);
        acc[2] = fmaf(__uint_as_float(a.y << 16), w, acc[2]);
        acc[3] = fmaf(__uint_as_float(a.y & 0xffff0000u), w, acc[3]);
        acc[4] = fmaf(__uint_as_float(a.z << 16), w, acc[4]);
        acc[5] = fmaf(__uint_as_float(a.z & 0xffff0000u), w, acc[5]);
        acc[6] = fmaf(__uint_as_float(a.w << 16), w, acc[6]);
        acc[7] = fmaf(__uint_as_float(a.w & 0xffff0000u), w, acc[7]);
    }
#pragma unroll
    for (int j = 0; j < 8; ++j) acc[j] += __shfl_xor(acc[j], 32, 64);
    if (half == 0) {
        uint4 o;
        o.x = pack2(acc[0], acc[1]);
        o.y = pack2(acc[2], acc[3]);
        o.z = pack2(acc[4], acc[5]);
        o.w = pack2(acc[6], acc[7]);
        *(uint4*)(ptrb + (size_t)v * D + c * 8) = o;
    }
}

// ---- MFMA dual-head GEMM + bias + softplus + rsample, register-prefetch pipeline ----
__global__ __launch_bounds__(256) void head_mfma_kernel(const unsigned short* __restrict__ ptrb,
                                                        const unsigned short* __restrict__ wT,
                                                        const float* __restrict__ lb,
                                                        const float* __restrict__ sb,
                                                        const float* __restrict__ eps,
                                                        float* __restrict__ out, int V) {
    __shared__ unsigned short lA[BM][72];
    __shared__ unsigned short lB[BM][72];
    int c0 = blockIdx.x * 64;
    int v0 = blockIdx.y * BM;
    int tid = threadIdx.x;
    int wave = tid >> 6, lane = tid & 63;
    int quad = lane >> 4, m16 = lane & 15;
    bool fullA = (v0 + BM <= V);

    int sc_m[4], sc_kc[4], sc_n[4];
#pragma unroll
    for (int it = 0; it < 4; ++it) {
        int cc = it * 256 + tid;
        int m = cc >> 3, kc = (cc & 7) * 8;
        sc_m[it] = m; sc_kc[it] = kc;
        sc_n[it] = (m < 64) ? (c0 + m) : (D + c0 + (m - 64));
    }

    uint4 ra[4], rb[4];
#pragma unroll
    for (int it = 0; it < 4; ++it) {
        int vv = v0 + sc_m[it];
        ra[it] = (fullA || vv < V) ? *(const uint4*)(ptrb + (size_t)vv * D + sc_kc[it])
                                   : make_uint4(0, 0, 0, 0);
        rb[it] = *(const uint4*)(wT + (size_t)sc_n[it] * D + sc_kc[it]);
    }

    f32x4 acc[2][8];
    f32x4 zero = {0.f, 0.f, 0.f, 0.f};
#pragma unroll
    for (int i = 0; i < 2; ++i)
#pragma unroll
        for (int j = 0; j < 8; ++j) acc[i][j] = zero;

    for (int k0i = 0; k0i < 4; ++k0i) {
        if (k0i) __syncthreads();
#pragma unroll
        for (int it = 0; it < 4; ++it) {
            *(uint4*)&lA[sc_m[it]][sc_kc[it]] = ra[it];
            *(uint4*)&lB[sc_m[it]][sc_kc[it]] = rb[it];
        }
        __syncthreads();
        if (k0i < 3) {
            int k0 = (k0i + 1) * 64;
#pragma unroll
            for (int it = 0; it < 4; ++it) {
                int vv = v0 + sc_m[it];
                ra[it] = (fullA || vv < V) ? *(const uint4*)(ptrb + (size_t)vv * D + k0 + sc_kc[it])
                                           : make_uint4(0, 0, 0, 0);
                rb[it] = *(const uint4*)(wT + (size_t)sc_n[it] * D + k0 + sc_kc[it]);
            }
        }
#pragma unroll
        for (int kk = 0; kk < 2; ++kk) {
            int kb = kk * 32 + quad * 8;
            s16x8 a0 = *(const s16x8*)&lA[wave * 32 + m16][kb];
            s16x8 a1 = *(const s16x8*)&lA[wave * 32 + 16 + m16][kb];
#pragma unroll
            for (int nt = 0; nt < 8; ++nt) {
                s16x8 b = *(const s16x8*)&lB[nt * 16 + m16][kb];
                acc[0][nt] = __builtin_amdgcn_mfma_f32_16x16x32_bf16(a0, b, acc[0][nt], 0, 0, 0);
                acc[1][nt] = __builtin_amdgcn_mfma_f32_16x16x32_bf16(a1, b, acc[1][nt], 0, 0, 0);
            }
        }
    }

    size_t VD = (size_t)V * D;
    float lbv[4], sbv[4];
#pragma unroll
    for (int nt = 0; nt < 4; ++nt) {
        int cc = c0 + nt * 16 + m16;
        lbv[nt] = lb[cc];
        sbv[nt] = sb[cc];
    }
    const float* epsb = eps + (size_t)v0 * D;
    float* outb = out + (size_t)v0 * D;
#pragma unroll
    for (int mt = 0; mt < 2; ++mt) {
#pragma unroll
        for (int nt = 0; nt < 4; ++nt) {
#pragma unroll
            for (int r = 0; r < 4; ++r) {
                int row = wave * 32 + mt * 16 + quad * 4 + r;
                if (fullA || v0 + row < V) {
                    int o = row * D + c0 + nt * 16 + m16;
                    float lo = acc[mt][nt][r] + lbv[nt];
                    float pre = acc[mt][nt + 4][r] + sbv[nt];
                    float sp = fmaxf(pre, 0.f) + __logf(1.f + __expf(-fabsf(pre)));
                    float st = sp + 1e-7f;
                    float ep = __builtin_nontemporal_load(&epsb[o]);
                    __builtin_nontemporal_store(lo, &outb[o]);
                    __builtin_nontemporal_store(st, &outb[VD + o]);
                    __builtin_nontemporal_store(fmaf(st, ep, lo), &outb[2 * VD + o]);
                }
            }
        }
    }
}

extern "C" void kernel_launch(void* const* d_in, const int* in_sizes, int n_in,
                              void* d_out, int out_size, void* d_ws, size_t ws_size,
                              hipStream_t stream) {
    const float* vrepr = (const float*)d_in[0];
    const int*   sidx  = (const int*)d_in[1];
    const int*   tidx  = (const int*)d_in[2];
    const float* esgn  = (const float*)d_in[3];
    const float* enorm = (const float*)d_in[4];
    const float* loc_w = (const float*)d_in[5];
    const float* loc_b = (const float*)d_in[6];
    const float* std_w = (const float*)d_in[7];
    const float* std_b = (const float*)d_in[8];
    const float* eps   = (const float*)d_in[9];
    float* out = (float*)d_out;

    int E = in_sizes[1];
    int V = in_sizes[0] / D;

    char* ws = (char*)d_ws;
    size_t o = 0;
    unsigned short* vb   = (unsigned short*)(ws + o); o += (size_t)V * D * 2;
    unsigned short* ptrb = (unsigned short*)(ws + o); o += (size_t)V * D * 2;
    unsigned short* wT   = (unsigned short*)(ws + o); o += (size_t)2 * D * D * 2;
    int* off  = (int*)(ws + o); o += ((size_t)V + 16) * sizeof(int);
    int* cnt  = (int*)(ws + o); o += ((size_t)V + 16) * sizeof(int);
    int* rank = (int*)(ws + o); o += (size_t)E * sizeof(int);
    o = (o + 15) & ~(size_t)15;
    int2* pk = (int2*)(ws + o); o += (size_t)E * sizeof(int2);

    hipMemsetAsync(cnt, 0, (size_t)V * sizeof(int), stream);
    prep_w_kernel<<<(2 * D * D) / 256, 256, 0, stream>>>(loc_w, std_w, wT);
    conv_v_kernel<<<(V * (D / 8) + 255) / 256, 256, 0, stream>>>(vrepr, vb, V * (D / 8));
    hist_kernel<<<(E + 255) / 256, 256, 0, stream>>>(tidx, cnt, rank, E);
    scan_kernel<<<1, 1024, 0, stream>>>(cnt, off, V, E);
    fill_kernel<<<(E + 255) / 256, 256, 0, stream>>>(sidx, tidx, esgn, enorm, off, rank, pk, E);
    accum_kernel<<<(V * 64 + 255) / 256, 256, 0, stream>>>(vb, pk, off, ptrb, V);
    dim3 hgrid(4, (V + BM - 1) / BM);
    head_mfma_kernel<<<hgrid, 256, 0, stream>>>(ptrb, wT, loc_b, std_b, eps, out, V);
}